// Round 1
// baseline (2973.901 us; speedup 1.0000x reference)
//
#include <hip/hip_runtime.h>
#include <hip/hip_fp16.h>
#include <cstdint>
#include <cstddef>

#define B_ 2
#define C_ 64
#define H_ 256
#define W_ 256
#define HW_ (H_*W_)
#define DG_ 8
#define CG_ 8
#define KK_ 9
#define NOFF_ 144
#define NMSK_ 72
#define NTOT_ 216
#define KRED_ 1152   // 128 * 9

// ---------------- kernel 0: weight transpose -> wT[(g*8+c)*9+k][o] ----------------
__global__ void wtrans_kernel(const float* __restrict__ w, float* __restrict__ wT) {
    int idx = blockIdx.x * 256 + threadIdx.x;   // 36864 = 576*64 total
    int ck = idx >> 6;     // (g*8+c)*9+k
    int o  = idx & 63;
    wT[idx] = w[o * 576 + ck];
}

// ---------------- kernel 1: offset/mask conv (implicit GEMM, fp32) ----------------
// tile M=128 positions x N=64 channels, K-chunk 16, 128 threads, 8x8 microtile
__global__ __launch_bounds__(128) void conv_kernel(
    const float* __restrict__ ref, const float* __restrict__ nbr,
    const float* __restrict__ off_w, const float* __restrict__ off_b,
    const float* __restrict__ msk_w, const float* __restrict__ msk_b,
    __half* __restrict__ off_o, __half* __restrict__ msk_o)
{
    __shared__ float As[16][132];   // [k][m], row stride 132 (16B aligned)
    __shared__ float Bs[16][68];    // [k][n]
    const int tid = threadIdx.x;
    const int mt = blockIdx.x;      // 0..1023
    const int nt = blockIdx.y;      // 0..3
    const int m0 = mt * 128;
    const int b  = m0 >> 16;
    const int h  = (m0 >> 8) & 255;
    const int w0 = m0 & 255;        // 0 or 128
    const int tx = tid & 15;
    const int ty = tid >> 4;        // 0..7

    float acc[8][8];
    #pragma unroll
    for (int i = 0; i < 8; ++i)
        #pragma unroll
        for (int j = 0; j < 8; ++j) acc[i][j] = 0.f;

    const int bk  = tid & 15;
    const int bn0 = tid >> 4;

    for (int k0 = 0; k0 < KRED_; k0 += 16) {
        // ---- stage A: 16 k x 128 m (im2col on the fly, zero-pad borders)
        #pragma unroll
        for (int kl = 0; kl < 16; ++kl) {
            int k  = k0 + kl;
            int ci = k / 9;              // 0..127
            int r  = k - ci * 9;
            int kh = r / 3;
            int kw = r - kh * 3;
            int y = h + kh - 1;
            int x = w0 + tid + kw - 1;
            const float* src = (ci < 64) ? ref : nbr;
            float v = 0.f;
            if ((unsigned)y < H_ && (unsigned)x < W_)
                v = src[((size_t)(b * 64 + (ci & 63)) * H_ + y) * W_ + x];
            As[kl][tid] = v;
        }
        // ---- stage B: 16 k x 64 n (off_w then msk_w; pad n>=216 with 0)
        #pragma unroll
        for (int s = 0; s < 8; ++s) {
            int nl = bn0 + s * 8;
            int n  = nt * 64 + nl;
            int k  = k0 + bk;
            float v = 0.f;
            if (n < NOFF_)       v = off_w[(size_t)n * KRED_ + k];
            else if (n < NTOT_)  v = msk_w[(size_t)(n - NOFF_) * KRED_ + k];
            Bs[bk][nl] = v;
        }
        __syncthreads();
        #pragma unroll
        for (int kk = 0; kk < 16; ++kk) {
            float4 a0 = *(const float4*)&As[kk][tx * 8];
            float4 a1 = *(const float4*)&As[kk][tx * 8 + 4];
            float4 b0 = *(const float4*)&Bs[kk][ty * 8];
            float4 b1 = *(const float4*)&Bs[kk][ty * 8 + 4];
            float av[8] = {a0.x,a0.y,a0.z,a0.w,a1.x,a1.y,a1.z,a1.w};
            float bv[8] = {b0.x,b0.y,b0.z,b0.w,b1.x,b1.y,b1.z,b1.w};
            #pragma unroll
            for (int i = 0; i < 8; ++i)
                #pragma unroll
                for (int j = 0; j < 8; ++j)
                    acc[i][j] += av[i] * bv[j];
        }
        __syncthreads();
    }

    // ---- epilogue: +bias, sigmoid for mask channels, f16 store
    #pragma unroll
    for (int j = 0; j < 8; ++j) {
        int n = nt * 64 + ty * 8 + j;
        if (n >= NTOT_) continue;
        bool is_off = (n < NOFF_);
        float bia = is_off ? off_b[n] : msk_b[n - NOFF_];
        union { uint4 u; __half hx[8]; } pk;
        #pragma unroll
        for (int i = 0; i < 8; ++i) {
            float v = acc[i][j] + bia;
            if (!is_off) v = 1.f / (1.f + __expf(-v));
            pk.hx[i] = __float2half(v);
        }
        int w = w0 + tx * 8;
        __half* dst = is_off
            ? (off_o + ((size_t)(b * NOFF_ + n) * H_ + h) * W_ + w)
            : (msk_o + ((size_t)(b * NMSK_ + (n - NOFF_)) * H_ + h) * W_ + w);
        *(uint4*)dst = pk.u;
    }
}

// ---------------- kernel 2: bilinear sample + modulated einsum ----------------
// one thread per pixel; block = one (b,h) row of 256 pixels; loop over groups
__global__ __launch_bounds__(256) void apply_kernel(
    const float* __restrict__ nbr, const __half* __restrict__ off_o,
    const __half* __restrict__ msk_o, const float* __restrict__ wT,
    const float* __restrict__ bias, float* __restrict__ out)
{
    __shared__ float wl[CG_ * KK_ * 64];   // 4608 floats = 18 KB, one group slice
    const int tid = threadIdx.x;
    const int bh = blockIdx.x;     // b*H + h
    const int b = bh >> 8;
    const int h = bh & 255;
    const int w = tid;

    float4 acc[16];
    #pragma unroll
    for (int j = 0; j < 16; ++j)
        acc[j] = make_float4(bias[4*j], bias[4*j+1], bias[4*j+2], bias[4*j+3]);

    const int pix = h * W_ + w;

    for (int g = 0; g < DG_; ++g) {
        __syncthreads();
        for (int t = tid; t < CG_ * KK_ * 64; t += 256)
            wl[t] = wT[g * (CG_ * KK_ * 64) + t];
        __syncthreads();
        const float*  nbg  = nbr   + ((size_t)b * C_ + g * CG_) * HW_;
        const __half* offp = off_o + ((size_t)(b * NOFF_ + g * 18)) * HW_ + pix;
        const __half* mskp = msk_o + ((size_t)(b * NMSK_ + g * 9)) * HW_ + pix;
        #pragma unroll 1
        for (int k = 0; k < 9; ++k) {
            float dy = __half2float(offp[(size_t)(2*k)     * HW_]);
            float dx = __half2float(offp[(size_t)(2*k + 1) * HW_]);
            float mm = __half2float(mskp[(size_t)k * HW_]);
            float ys = (float)(h - 1 + k / 3) + dy;
            float xs = (float)(w - 1 + k % 3) + dx;
            float y0f = floorf(ys), x0f = floorf(xs);
            float wy = ys - y0f, wx = xs - x0f;
            int y0 = (int)y0f, x0 = (int)x0f;
            int y1 = y0 + 1, x1 = x0 + 1;
            float v00 = ((unsigned)y0 < H_ && (unsigned)x0 < W_) ? 1.f : 0.f;
            float v01 = ((unsigned)y0 < H_ && (unsigned)x1 < W_) ? 1.f : 0.f;
            float v10 = ((unsigned)y1 < H_ && (unsigned)x0 < W_) ? 1.f : 0.f;
            float v11 = ((unsigned)y1 < H_ && (unsigned)x1 < W_) ? 1.f : 0.f;
            int yc0 = min(max(y0, 0), H_-1), yc1 = min(max(y1, 0), H_-1);
            int xc0 = min(max(x0, 0), W_-1), xc1 = min(max(x1, 0), W_-1);
            float w00 = (1.f-wy)*(1.f-wx)*mm*v00;
            float w01 = (1.f-wy)*wx*mm*v01;
            float w10 = wy*(1.f-wx)*mm*v10;
            float w11 = wy*wx*mm*v11;
            int o00 = yc0*W_ + xc0, o01 = yc0*W_ + xc1;
            int o10 = yc1*W_ + xc0, o11 = yc1*W_ + xc1;
            #pragma unroll
            for (int c = 0; c < CG_; ++c) {
                const float* p = nbg + (size_t)c * HW_;
                float v = w00*p[o00] + w01*p[o01] + w10*p[o10] + w11*p[o11];
                const float* wp = &wl[(c * 9 + k) * 64];
                #pragma unroll
                for (int j = 0; j < 16; ++j) {
                    float4 wv = *(const float4*)(wp + 4*j);
                    acc[j].x += v * wv.x;
                    acc[j].y += v * wv.y;
                    acc[j].z += v * wv.z;
                    acc[j].w += v * wv.w;
                }
            }
        }
    }

    float* op = out + (size_t)b * C_ * HW_ + pix;
    #pragma unroll
    for (int j = 0; j < 16; ++j) {
        op[(size_t)(4*j+0)*HW_] = acc[j].x;
        op[(size_t)(4*j+1)*HW_] = acc[j].y;
        op[(size_t)(4*j+2)*HW_] = acc[j].z;
        op[(size_t)(4*j+3)*HW_] = acc[j].w;
    }
}

extern "C" void kernel_launch(void* const* d_in, const int* in_sizes, int n_in,
                              void* d_out, int out_size, void* d_ws, size_t ws_size,
                              hipStream_t stream) {
    const float* ref    = (const float*)d_in[0];
    const float* nbr    = (const float*)d_in[1];
    const float* off_w  = (const float*)d_in[2];
    const float* off_b  = (const float*)d_in[3];
    const float* msk_w  = (const float*)d_in[4];
    const float* msk_b  = (const float*)d_in[5];
    const float* weight = (const float*)d_in[6];
    const float* bias   = (const float*)d_in[7];
    float* out = (float*)d_out;

    // workspace carve: wT (147456 B) | off f16 (37748736 B) | msk f16 (18874368 B)
    float*  wT    = (float*)d_ws;
    __half* off_o = (__half*)((char*)d_ws + (size_t)64 * 576 * 4);
    __half* msk_o = off_o + (size_t)B_ * NOFF_ * HW_;

    wtrans_kernel<<<144, 256, 0, stream>>>(weight, wT);
    conv_kernel<<<dim3(1024, 4), 128, 0, stream>>>(ref, nbr, off_w, off_b,
                                                   msk_w, msk_b, off_o, msk_o);
    apply_kernel<<<B_ * H_, 256, 0, stream>>>(nbr, off_o, msk_o, wT, bias, out);
}

// Round 2
// 769.178 us; speedup vs baseline: 3.8663x; 3.8663x over previous
//
#include <hip/hip_runtime.h>
#include <hip/hip_fp16.h>
#include <cstdint>
#include <cstddef>

#define B_ 2
#define C_ 64
#define H_ 256
#define W_ 256
#define HW_ (H_*W_)
#define DG_ 8
#define CG_ 8
#define KK_ 9
#define NOFF_ 144
#define NMSK_ 72
#define NTOT_ 216
#define NPAD_ 224
#define KRED_ 1152   // 128 * 9

typedef __bf16 bf16x8 __attribute__((ext_vector_type(8)));
typedef short  short8 __attribute__((ext_vector_type(8)));
typedef float  f32x4  __attribute__((ext_vector_type(4)));

__device__ __forceinline__ short f2bf(float f) {
    union { float f; uint32_t u; } a; a.f = f;
    uint32_t u = a.u;
    uint32_t r = (u + 0x7fffu + ((u >> 16) & 1u)) >> 16;
    return (short)r;
}

// ---------------- kernel 0a: weight transpose (fp32, for apply) ----------------
__global__ void wtrans_kernel(const float* __restrict__ w, float* __restrict__ wT) {
    int idx = blockIdx.x * 256 + threadIdx.x;   // 36864 = 576*64
    int ck = idx >> 6;
    int o  = idx & 63;
    wT[idx] = w[o * 576 + ck];
}

// ---------------- kernel 0b: conv weights -> bf16, tap-major K, padded N --------
// Bw[n][r*128 + c] = W[n][c][r] (n<144: off_w, 144..215: msk_w, else 0)
__global__ void wtrans2_kernel(const float* __restrict__ off_w,
                               const float* __restrict__ msk_w,
                               short* __restrict__ Bw) {
    int idx = blockIdx.x * 256 + threadIdx.x;   // 224*1152 = 258048
    int n = idx / KRED_;
    int k = idx - n * KRED_;
    int r = k >> 7;           // tap 0..8
    int c = k & 127;          // channel 0..127
    float v = 0.f;
    if (n < NOFF_)      v = off_w[(size_t)n * KRED_ + c * 9 + r];
    else if (n < NTOT_) v = msk_w[(size_t)(n - NOFF_) * KRED_ + c * 9 + r];
    Bw[idx] = f2bf(v);
}

// ---------------- kernel 1: offset/mask conv — bf16 MFMA implicit GEMM ----------
// M-tile 128 px (half row, uniform h), N-tile 128 ch, BK=32 (one tap x 32 ch)
__global__ __launch_bounds__(256) void conv_mfma(
    const float* __restrict__ ref, const float* __restrict__ nbr,
    const short* __restrict__ Bw,
    const float* __restrict__ off_b, const float* __restrict__ msk_b,
    __half* __restrict__ off_o, __half* __restrict__ msk_o)
{
    __shared__ short As[4][128][8];   // [quad][m][j]  k = quad*8+j
    __shared__ short Bs[4][128][8];   // [quad][n][j]

    const int tid  = threadIdx.x;
    const int lane = tid & 63;
    const int wid  = tid >> 6;
    const int wm   = wid & 1;        // wave m-half
    const int wn   = wid >> 1;       // wave n-half

    const int m0 = blockIdx.x * 128;
    const int b  = m0 >> 16;
    const int h  = (m0 >> 8) & 255;
    const int w0 = m0 & 255;          // 0 or 128
    const int nbase = blockIdx.y * 128;

    // staging roles
    const int p    = tid & 127;       // A: pixel
    const int half = tid >> 7;        // A: channel half (16 ch)
    const int bn   = tid & 127;       // B: n
    const int bqp  = tid >> 7;        // B: quad pair

    const int col     = lane & 15;
    const int rowbase = (lane >> 4) * 4;
    const int quad    = lane >> 4;

    f32x4 acc[4][4];
    #pragma unroll
    for (int i = 0; i < 4; ++i)
        #pragma unroll
        for (int j = 0; j < 4; ++j) acc[i][j] = f32x4{0.f, 0.f, 0.f, 0.f};

    for (int kc = 0; kc < 36; ++kc) {
        const int r  = kc >> 2;             // tap 0..8
        const int c0 = (kc & 3) * 32;       // channel base of chunk
        const int y  = h + (r / 3) - 1;
        if ((unsigned)y >= H_) continue;    // block-uniform skip (zero tap row)

        // ---- stage A: 128 px x 32 ch (fp32 load -> bf16)
        {
            const int x = w0 + p + (r % 3) - 1;
            const bool valid = (unsigned)x < W_;
            const int cstart = c0 + half * 16;
            const float* base = (cstart < 64)
                ? (ref + (size_t)(b * 64 + cstart) * HW_)
                : (nbr + (size_t)(b * 64 + (cstart - 64)) * HW_);
            const size_t yx = (size_t)y * W_ + x;
            float v[16];
            if (valid) {
                #pragma unroll
                for (int j = 0; j < 16; ++j) v[j] = base[(size_t)j * HW_ + yx];
            } else {
                #pragma unroll
                for (int j = 0; j < 16; ++j) v[j] = 0.f;
            }
            #pragma unroll
            for (int jj2 = 0; jj2 < 2; ++jj2) {
                short8 s;
                #pragma unroll
                for (int j = 0; j < 8; ++j) s[j] = f2bf(v[jj2 * 8 + j]);
                *reinterpret_cast<short8*>(&As[half * 2 + jj2][p][0]) = s;
            }
        }
        // ---- stage B: 128 n x 32 k from Bw
        {
            #pragma unroll
            for (int qq = 0; qq < 2; ++qq) {
                int q = bqp * 2 + qq;
                short8 s = *reinterpret_cast<const short8*>(
                    Bw + (size_t)(nbase + bn) * KRED_ + kc * 32 + q * 8);
                *reinterpret_cast<short8*>(&Bs[q][bn][0]) = s;
            }
        }
        __syncthreads();

        // ---- fragments + MFMA
        bf16x8 af[4], bf[4];
        #pragma unroll
        for (int mt = 0; mt < 4; ++mt)
            af[mt] = *reinterpret_cast<bf16x8*>(&As[quad][wm * 64 + mt * 16 + col][0]);
        #pragma unroll
        for (int nt = 0; nt < 4; ++nt)
            bf[nt] = *reinterpret_cast<bf16x8*>(&Bs[quad][wn * 64 + nt * 16 + col][0]);
        #pragma unroll
        for (int mt = 0; mt < 4; ++mt)
            #pragma unroll
            for (int nt = 0; nt < 4; ++nt)
                acc[mt][nt] = __builtin_amdgcn_mfma_f32_16x16x32_bf16(
                    af[mt], bf[nt], acc[mt][nt], 0, 0, 0);
        __syncthreads();
    }

    // ---- epilogue: +bias, sigmoid for mask, f16 store (4 consecutive px / lane)
    #pragma unroll
    for (int mt = 0; mt < 4; ++mt) {
        const int wloc = w0 + wm * 64 + mt * 16 + rowbase;
        #pragma unroll
        for (int nt = 0; nt < 4; ++nt) {
            const int n = nbase + wn * 64 + nt * 16 + col;
            if (n >= NTOT_) continue;
            const bool is_off = (n < NOFF_);
            const float bia = is_off ? off_b[n] : msk_b[n - NOFF_];
            union { uint2 u; __half hx[4]; } pk;
            #pragma unroll
            for (int rr = 0; rr < 4; ++rr) {
                float v = acc[mt][nt][rr] + bia;
                if (!is_off) v = 1.f / (1.f + __expf(-v));
                pk.hx[rr] = __float2half(v);
            }
            __half* dst = is_off
                ? (off_o + ((size_t)(b * NOFF_ + n) * H_ + h) * W_ + wloc)
                : (msk_o + ((size_t)(b * NMSK_ + (n - NOFF_)) * H_ + h) * W_ + wloc);
            *(uint2*)dst = pk.u;
        }
    }
}

// ---------------- kernel 2: bilinear sample + modulated einsum ----------------
__global__ __launch_bounds__(256) void apply_kernel(
    const float* __restrict__ nbr, const __half* __restrict__ off_o,
    const __half* __restrict__ msk_o, const float* __restrict__ wT,
    const float* __restrict__ bias, float* __restrict__ out)
{
    __shared__ float wl[CG_ * KK_ * 64];   // 18 KB, one group slice
    const int tid = threadIdx.x;
    const int bh = blockIdx.x;
    const int b = bh >> 8;
    const int h = bh & 255;
    const int w = tid;

    float4 acc[16];
    #pragma unroll
    for (int j = 0; j < 16; ++j)
        acc[j] = make_float4(bias[4*j], bias[4*j+1], bias[4*j+2], bias[4*j+3]);

    const int pix = h * W_ + w;

    for (int g = 0; g < DG_; ++g) {
        __syncthreads();
        for (int t = tid; t < CG_ * KK_ * 64; t += 256)
            wl[t] = wT[g * (CG_ * KK_ * 64) + t];
        __syncthreads();
        const float*  nbg  = nbr   + ((size_t)b * C_ + g * CG_) * HW_;
        const __half* offp = off_o + ((size_t)(b * NOFF_ + g * 18)) * HW_ + pix;
        const __half* mskp = msk_o + ((size_t)(b * NMSK_ + g * 9)) * HW_ + pix;
        #pragma unroll 1
        for (int k = 0; k < 9; ++k) {
            float dy = __half2float(offp[(size_t)(2*k)     * HW_]);
            float dx = __half2float(offp[(size_t)(2*k + 1) * HW_]);
            float mm = __half2float(mskp[(size_t)k * HW_]);
            float ys = (float)(h - 1 + k / 3) + dy;
            float xs = (float)(w - 1 + k % 3) + dx;
            float y0f = floorf(ys), x0f = floorf(xs);
            float wy = ys - y0f, wx = xs - x0f;
            int y0 = (int)y0f, x0 = (int)x0f;
            int y1 = y0 + 1, x1 = x0 + 1;
            float v00 = ((unsigned)y0 < H_ && (unsigned)x0 < W_) ? 1.f : 0.f;
            float v01 = ((unsigned)y0 < H_ && (unsigned)x1 < W_) ? 1.f : 0.f;
            float v10 = ((unsigned)y1 < H_ && (unsigned)x0 < W_) ? 1.f : 0.f;
            float v11 = ((unsigned)y1 < H_ && (unsigned)x1 < W_) ? 1.f : 0.f;
            int yc0 = min(max(y0, 0), H_-1), yc1 = min(max(y1, 0), H_-1);
            int xc0 = min(max(x0, 0), W_-1), xc1 = min(max(x1, 0), W_-1);
            float w00 = (1.f-wy)*(1.f-wx)*mm*v00;
            float w01 = (1.f-wy)*wx*mm*v01;
            float w10 = wy*(1.f-wx)*mm*v10;
            float w11 = wy*wx*mm*v11;
            int o00 = yc0*W_ + xc0, o01 = yc0*W_ + xc1;
            int o10 = yc1*W_ + xc0, o11 = yc1*W_ + xc1;
            #pragma unroll
            for (int c = 0; c < CG_; ++c) {
                const float* pch = nbg + (size_t)c * HW_;
                float v = w00*pch[o00] + w01*pch[o01] + w10*pch[o10] + w11*pch[o11];
                const float* wp = &wl[(c * 9 + k) * 64];
                #pragma unroll
                for (int j = 0; j < 16; ++j) {
                    float4 wv = *(const float4*)(wp + 4*j);
                    acc[j].x += v * wv.x;
                    acc[j].y += v * wv.y;
                    acc[j].z += v * wv.z;
                    acc[j].w += v * wv.w;
                }
            }
        }
    }

    float* op = out + (size_t)b * C_ * HW_ + pix;
    #pragma unroll
    for (int j = 0; j < 16; ++j) {
        op[(size_t)(4*j+0)*HW_] = acc[j].x;
        op[(size_t)(4*j+1)*HW_] = acc[j].y;
        op[(size_t)(4*j+2)*HW_] = acc[j].z;
        op[(size_t)(4*j+3)*HW_] = acc[j].w;
    }
}

extern "C" void kernel_launch(void* const* d_in, const int* in_sizes, int n_in,
                              void* d_out, int out_size, void* d_ws, size_t ws_size,
                              hipStream_t stream) {
    const float* ref    = (const float*)d_in[0];
    const float* nbr    = (const float*)d_in[1];
    const float* off_w  = (const float*)d_in[2];
    const float* off_b  = (const float*)d_in[3];
    const float* msk_w  = (const float*)d_in[4];
    const float* msk_b  = (const float*)d_in[5];
    const float* weight = (const float*)d_in[6];
    const float* bias   = (const float*)d_in[7];
    float* out = (float*)d_out;

    // ws carve: wT fp32 (147456 B) | off f16 (37748736 B) | msk f16 (18874368 B)
    //           | Bw bf16 (516096 B)
    float*  wT    = (float*)d_ws;
    __half* off_o = (__half*)((char*)d_ws + (size_t)64 * 576 * 4);
    __half* msk_o = off_o + (size_t)B_ * NOFF_ * HW_;
    short*  Bw    = (short*)((char*)d_ws + (size_t)64*576*4
                              + (size_t)B_*NOFF_*HW_*2 + (size_t)B_*NMSK_*HW_*2);

    wtrans_kernel<<<144, 256, 0, stream>>>(weight, wT);
    wtrans2_kernel<<<1008, 256, 0, stream>>>(off_w, msk_w, Bw);
    conv_mfma<<<dim3(1024, 2), 256, 0, stream>>>(ref, nbr, Bw, off_b, msk_b,
                                                 off_o, msk_o);
    apply_kernel<<<B_ * H_, 256, 0, stream>>>(nbr, off_o, msk_o, wT, bias, out);
}

// Round 3
// 558.587 us; speedup vs baseline: 5.3240x; 1.3770x over previous
//
#include <hip/hip_runtime.h>
#include <hip/hip_fp16.h>
#include <cstdint>
#include <cstddef>

#define B_ 2
#define C_ 64
#define H_ 256
#define W_ 256
#define HW_ (H_*W_)
#define DG_ 8
#define CG_ 8
#define KK_ 9
#define NOFF_ 144
#define NMSK_ 72
#define NTOT_ 216
#define NPAD_ 224
#define KRED_ 1152   // 128 * 9

typedef __bf16 bf16x8 __attribute__((ext_vector_type(8)));
typedef short  short8 __attribute__((ext_vector_type(8)));
typedef float  f32x4  __attribute__((ext_vector_type(4)));

__device__ __forceinline__ short f2bf(float f) {
    union { float f; uint32_t u; } a; a.f = f;
    uint32_t u = a.u;
    uint32_t r = (u + 0x7fffu + ((u >> 16) & 1u)) >> 16;
    return (short)r;
}

// ---------------- kernel 0a: weight transpose (fp32, for apply) ----------------
__global__ void wtrans_kernel(const float* __restrict__ w, float* __restrict__ wT) {
    int idx = blockIdx.x * 256 + threadIdx.x;   // 36864 = 576*64
    int ck = idx >> 6;
    int o  = idx & 63;
    wT[idx] = w[o * 576 + ck];
}

// ---------------- kernel 0b: conv weights -> bf16, tap-major K, padded N --------
__global__ void wtrans2_kernel(const float* __restrict__ off_w,
                               const float* __restrict__ msk_w,
                               short* __restrict__ Bw) {
    int idx = blockIdx.x * 256 + threadIdx.x;   // 224*1152 = 258048
    int n = idx / KRED_;
    int k = idx - n * KRED_;
    int r = k >> 7;           // tap 0..8
    int c = k & 127;          // channel 0..127
    float v = 0.f;
    if (n < NOFF_)      v = off_w[(size_t)n * KRED_ + c * 9 + r];
    else if (n < NTOT_) v = msk_w[(size_t)(n - NOFF_) * KRED_ + c * 9 + r];
    Bw[idx] = f2bf(v);
}

// ---------------- kernel 0c: out = bias (for atomic accumulation) ---------------
__global__ void init_out(const float* __restrict__ bias, float* __restrict__ out) {
    int i = blockIdx.x * 256 + threadIdx.x;   // 2097152 float4s
    int ch = (i >> 14) & 63;                  // elem = i*4; ch = (elem>>16)&63
    float bv = bias[ch];
    ((float4*)out)[i] = make_float4(bv, bv, bv, bv);
}

// ---------------- kernel 1: offset/mask conv — bf16 MFMA implicit GEMM ----------
__global__ __launch_bounds__(256) void conv_mfma(
    const float* __restrict__ ref, const float* __restrict__ nbr,
    const short* __restrict__ Bw,
    const float* __restrict__ off_b, const float* __restrict__ msk_b,
    __half* __restrict__ off_o, __half* __restrict__ msk_o)
{
    __shared__ short As[4][128][8];   // [quad][m][j]  k = quad*8+j
    __shared__ short Bs[4][128][8];   // [quad][n][j]

    const int tid  = threadIdx.x;
    const int lane = tid & 63;
    const int wid  = tid >> 6;
    const int wm   = wid & 1;
    const int wn   = wid >> 1;

    const int m0 = blockIdx.x * 128;
    const int b  = m0 >> 16;
    const int h  = (m0 >> 8) & 255;
    const int w0 = m0 & 255;
    const int nbase = blockIdx.y * 128;

    const int p    = tid & 127;
    const int half = tid >> 7;
    const int bn   = tid & 127;
    const int bqp  = tid >> 7;

    const int col     = lane & 15;
    const int rowbase = (lane >> 4) * 4;
    const int quad    = lane >> 4;

    f32x4 acc[4][4];
    #pragma unroll
    for (int i = 0; i < 4; ++i)
        #pragma unroll
        for (int j = 0; j < 4; ++j) acc[i][j] = f32x4{0.f, 0.f, 0.f, 0.f};

    for (int kc = 0; kc < 36; ++kc) {
        const int r  = kc >> 2;
        const int c0 = (kc & 3) * 32;
        const int y  = h + (r / 3) - 1;
        if ((unsigned)y >= H_) continue;

        {
            const int x = w0 + p + (r % 3) - 1;
            const bool valid = (unsigned)x < W_;
            const int cstart = c0 + half * 16;
            const float* base = (cstart < 64)
                ? (ref + (size_t)(b * 64 + cstart) * HW_)
                : (nbr + (size_t)(b * 64 + (cstart - 64)) * HW_);
            const size_t yx = (size_t)y * W_ + x;
            float v[16];
            if (valid) {
                #pragma unroll
                for (int j = 0; j < 16; ++j) v[j] = base[(size_t)j * HW_ + yx];
            } else {
                #pragma unroll
                for (int j = 0; j < 16; ++j) v[j] = 0.f;
            }
            #pragma unroll
            for (int jj2 = 0; jj2 < 2; ++jj2) {
                short8 s;
                #pragma unroll
                for (int j = 0; j < 8; ++j) s[j] = f2bf(v[jj2 * 8 + j]);
                *reinterpret_cast<short8*>(&As[half * 2 + jj2][p][0]) = s;
            }
        }
        {
            #pragma unroll
            for (int qq = 0; qq < 2; ++qq) {
                int q = bqp * 2 + qq;
                short8 s = *reinterpret_cast<const short8*>(
                    Bw + (size_t)(nbase + bn) * KRED_ + kc * 32 + q * 8);
                *reinterpret_cast<short8*>(&Bs[q][bn][0]) = s;
            }
        }
        __syncthreads();

        bf16x8 af[4], bf[4];
        #pragma unroll
        for (int mt = 0; mt < 4; ++mt)
            af[mt] = *reinterpret_cast<bf16x8*>(&As[quad][wm * 64 + mt * 16 + col][0]);
        #pragma unroll
        for (int nt = 0; nt < 4; ++nt)
            bf[nt] = *reinterpret_cast<bf16x8*>(&Bs[quad][wn * 64 + nt * 16 + col][0]);
        #pragma unroll
        for (int mt = 0; mt < 4; ++mt)
            #pragma unroll
            for (int nt = 0; nt < 4; ++nt)
                acc[mt][nt] = __builtin_amdgcn_mfma_f32_16x16x32_bf16(
                    af[mt], bf[nt], acc[mt][nt], 0, 0, 0);
        __syncthreads();
    }

    #pragma unroll
    for (int mt = 0; mt < 4; ++mt) {
        const int wloc = w0 + wm * 64 + mt * 16 + rowbase;
        #pragma unroll
        for (int nt = 0; nt < 4; ++nt) {
            const int n = nbase + wn * 64 + nt * 16 + col;
            if (n >= NTOT_) continue;
            const bool is_off = (n < NOFF_);
            const float bia = is_off ? off_b[n] : msk_b[n - NOFF_];
            union { uint2 u; __half hx[4]; } pk;
            #pragma unroll
            for (int rr = 0; rr < 4; ++rr) {
                float v = acc[mt][nt][rr] + bia;
                if (!is_off) v = 1.f / (1.f + __expf(-v));
                pk.hx[rr] = __float2half(v);
            }
            __half* dst = is_off
                ? (off_o + ((size_t)(b * NOFF_ + n) * H_ + h) * W_ + wloc)
                : (msk_o + ((size_t)(b * NMSK_ + (n - NOFF_)) * H_ + h) * W_ + wloc);
            *(uint2*)dst = pk.u;
        }
    }
}

// ---------------- kernel 2: bilinear sample + modulated einsum (group-split) ----
// grid (B*H rows, 4 splits); each block: 2 groups; atomicAdd into out (=bias)
__global__ __launch_bounds__(256) void apply_partial(
    const float* __restrict__ nbr, const __half* __restrict__ off_o,
    const __half* __restrict__ msk_o, const float* __restrict__ wT,
    float* __restrict__ out)
{
    __shared__ float wl[CG_ * KK_ * 64];   // 18 KB, one group slice
    const int tid = threadIdx.x;
    const int bh = blockIdx.x;
    const int b = bh >> 8;
    const int h = bh & 255;
    const int w = tid;
    const int g0 = blockIdx.y * 2;

    float4 acc[16];
    #pragma unroll
    for (int j = 0; j < 16; ++j) acc[j] = make_float4(0.f, 0.f, 0.f, 0.f);

    const int pix = h * W_ + w;

    for (int gi = 0; gi < 2; ++gi) {
        const int g = g0 + gi;
        __syncthreads();
        for (int t = tid; t < CG_ * KK_ * 64; t += 256)
            wl[t] = wT[g * (CG_ * KK_ * 64) + t];
        __syncthreads();
        const float*  nbg  = nbr   + ((size_t)b * C_ + g * CG_) * HW_;
        const __half* offp = off_o + ((size_t)(b * NOFF_ + g * 18)) * HW_ + pix;
        const __half* mskp = msk_o + ((size_t)(b * NMSK_ + g * 9)) * HW_ + pix;

        // prefetch all 27 offset/mask values (independent loads, overlap latency)
        float dyv[9], dxv[9], mmv[9];
        #pragma unroll
        for (int k = 0; k < 9; ++k) {
            dyv[k] = __half2float(offp[(size_t)(2*k)     * HW_]);
            dxv[k] = __half2float(offp[(size_t)(2*k + 1) * HW_]);
            mmv[k] = __half2float(mskp[(size_t)k * HW_]);
        }

        #pragma unroll 1
        for (int k = 0; k < 9; ++k) {
            float ys = (float)(h - 1 + k / 3) + dyv[k];
            float xs = (float)(w - 1 + k % 3) + dxv[k];
            float mm = mmv[k];
            float y0f = floorf(ys), x0f = floorf(xs);
            float wy = ys - y0f, wx = xs - x0f;
            int y0 = (int)y0f, x0 = (int)x0f;
            int y1 = y0 + 1, x1 = x0 + 1;
            // y rows: clamped address + validity-masked weight (mask folded in)
            int yc0 = min(max(y0, 0), H_-1), yc1 = min(max(y1, 0), H_-1);
            float wy0v = (1.f - wy) * (((unsigned)y0 < H_) ? mm : 0.f);
            float wy1v = wy * (((unsigned)y1 < H_) ? mm : 0.f);
            // x pair: one float2 covers both corners; remap weights to slots
            int xb = min(max(x0, 0), W_-2);
            float wx0v = (((unsigned)x0 < W_) ? (1.f - wx) : 0.f);
            float wx1v = (((unsigned)x1 < W_) ? wx : 0.f);
            float sx0 = (x0 == xb) ? wx0v : ((x1 == xb) ? wx1v : 0.f);
            float sx1 = (x1 == xb + 1) ? wx1v : ((x0 == xb + 1) ? wx0v : 0.f);
            int o0 = yc0 * W_ + xb, o1 = yc1 * W_ + xb;
            #pragma unroll
            for (int c = 0; c < CG_; ++c) {
                const float* pch = nbg + (size_t)c * HW_;
                float2 r0 = *(const float2*)(pch + o0);
                float2 r1 = *(const float2*)(pch + o1);
                float v = wy0v * (sx0 * r0.x + sx1 * r0.y)
                        + wy1v * (sx0 * r1.x + sx1 * r1.y);
                const float* wp = &wl[(c * 9 + k) * 64];
                #pragma unroll
                for (int j = 0; j < 16; ++j) {
                    float4 wv = *(const float4*)(wp + 4*j);
                    acc[j].x += v * wv.x;
                    acc[j].y += v * wv.y;
                    acc[j].z += v * wv.z;
                    acc[j].w += v * wv.w;
                }
            }
        }
    }

    float* op = out + (size_t)b * C_ * HW_ + pix;
    #pragma unroll
    for (int j = 0; j < 16; ++j) {
        atomicAdd(op + (size_t)(4*j+0)*HW_, acc[j].x);
        atomicAdd(op + (size_t)(4*j+1)*HW_, acc[j].y);
        atomicAdd(op + (size_t)(4*j+2)*HW_, acc[j].z);
        atomicAdd(op + (size_t)(4*j+3)*HW_, acc[j].w);
    }
}

extern "C" void kernel_launch(void* const* d_in, const int* in_sizes, int n_in,
                              void* d_out, int out_size, void* d_ws, size_t ws_size,
                              hipStream_t stream) {
    const float* ref    = (const float*)d_in[0];
    const float* nbr    = (const float*)d_in[1];
    const float* off_w  = (const float*)d_in[2];
    const float* off_b  = (const float*)d_in[3];
    const float* msk_w  = (const float*)d_in[4];
    const float* msk_b  = (const float*)d_in[5];
    const float* weight = (const float*)d_in[6];
    const float* bias   = (const float*)d_in[7];
    float* out = (float*)d_out;

    // ws carve: wT fp32 | off f16 | msk f16 | Bw bf16
    float*  wT    = (float*)d_ws;
    __half* off_o = (__half*)((char*)d_ws + (size_t)64 * 576 * 4);
    __half* msk_o = off_o + (size_t)B_ * NOFF_ * HW_;
    short*  Bw    = (short*)((char*)d_ws + (size_t)64*576*4
                              + (size_t)B_*NOFF_*HW_*2 + (size_t)B_*NMSK_*HW_*2);

    wtrans_kernel<<<144, 256, 0, stream>>>(weight, wT);
    wtrans2_kernel<<<1008, 256, 0, stream>>>(off_w, msk_w, Bw);
    init_out<<<8192, 256, 0, stream>>>(bias, out);
    conv_mfma<<<dim3(1024, 2), 256, 0, stream>>>(ref, nbr, Bw, off_b, msk_b,
                                                 off_o, msk_o);
    apply_partial<<<dim3(B_ * H_, 4), 256, 0, stream>>>(nbr, off_o, msk_o, wT, out);
}